// Round 12
// baseline (117.578 us; speedup 1.0000x reference)
//
#include <hip/hip_runtime.h>

// Problem constants
#define Bn  4
#define Cn  128
#define CQn 64
#define Nn  4096

typedef _Float16 h8_t __attribute__((ext_vector_type(8)));
typedef float    f32x4 __attribute__((ext_vector_type(4)));
typedef unsigned int u32;

// ws layout (bytes):
//  Qh: [B][N][64]  f16 at 0         (2 MB)
//  Kh: [B][N][64]  f16 at 2 MB      (2 MB)
//  Vg: [B][64 jt][128 c][64 pos] f16 at 4 MB (4 MB)  -- fragment-major V
//  pPart: [B][64 it][S][128 c][64 q] f32 at 8 MB   (S x 8 MB)
//  pMl:   [B][64 it][S][64 q][2]    f32 after      (S x 128 KB)

#define QKV_BYTES   8388608ull
#define PART_PER_S  8388608ull
#define ML_PER_S    131072ull

// ---------------------------------------------------------------------------
// Kernel 1: fused QKV projection. V is written FRAGMENT-MAJOR per 64-j tile:
// j stored at pos = 32h + 8g + (i&3) + 4*(i>=4), where j = 32h+4g+(i&3)+16(i>>2)
// -> each attn lane's 8-slot MFMA B-fragment is 16 contiguous bytes.
// For the proj's 4-consecutive-j group (a = j0/4): h=a>>3, qd=a&7,
// pos_base = 32h + (qd&3)*8 + (qd>>2)*4; the 4 j's land at pos_base..+3.
// ---------------------------------------------------------------------------
__global__ __launch_bounds__(256) void qkv_proj(
    const float* __restrict__ x,
    const float* __restrict__ Wq, const float* __restrict__ bq,
    const float* __restrict__ Wk, const float* __restrict__ bk,
    const float* __restrict__ Wv, const float* __restrict__ bv,
    _Float16* __restrict__ Qh, _Float16* __restrict__ Kh, _Float16* __restrict__ Vg)
{
    const int ntile = blockIdx.x;
    const int otile = blockIdx.y;
    const int b     = blockIdx.z;
    const int tid   = threadIdx.x;
    const int nbase = ntile * 64;

    __shared__ float Ws[64][132];
    __shared__ float Xs[128][68];

    const float* Wsrc; const float* bsrc; int obase;
    if (otile == 0)      { Wsrc = Wq;                     bsrc = bq;      obase = 0; }
    else if (otile == 1) { Wsrc = Wk;                     bsrc = bk;      obase = 0; }
    else                 { Wsrc = Wv + (otile - 2) * 64 * Cn;
                           bsrc = bv + (otile - 2) * 64;  obase = (otile - 2) * 64; }

    for (int u = 0; u < 8; ++u) {
        int f = tid + u * 256;
        int row = f >> 5;
        int col = (f & 31) * 4;
        *(float4*)&Ws[row][col] = *(const float4*)&Wsrc[row * Cn + col];
    }
    const float* xb = x + ((size_t)b * Cn) * Nn + nbase;
    for (int u = 0; u < 8; ++u) {
        int f = tid + u * 256;
        int c = f >> 4;
        int n = (f & 15) * 4;
        *(float4*)&Xs[c][n] = *(const float4*)&xb[(size_t)c * Nn + n];
    }
    __syncthreads();

    const int o0 = (tid >> 4) * 4;
    const int n0 = (tid & 15) * 4;
    float acc[4][4] = {};

    for (int c = 0; c < Cn; c += 4) {
        float4 w4[4], x4[4];
        for (int oo = 0; oo < 4; ++oo) w4[oo] = *(const float4*)&Ws[o0 + oo][c];
        for (int cc = 0; cc < 4; ++cc) x4[cc] = *(const float4*)&Xs[c + cc][n0];
        for (int oo = 0; oo < 4; ++oo) {
            const float* wv = (const float*)&w4[oo];
            for (int cc = 0; cc < 4; ++cc) {
                const float wsv = wv[cc];
                const float* xp = (const float*)&x4[cc];
                acc[oo][0] += wsv * xp[0];
                acc[oo][1] += wsv * xp[1];
                acc[oo][2] += wsv * xp[2];
                acc[oo][3] += wsv * xp[3];
            }
        }
    }

    float bias[4];
    for (int oo = 0; oo < 4; ++oo) bias[oo] = bsrc[o0 + oo];

    union H4 { _Float16 e[4]; short4 v; };

    if (otile <= 1) {
        _Float16* dst = (otile == 0 ? Qh : Kh) + ((size_t)b * Nn + nbase) * CQn;
        for (int nn = 0; nn < 4; ++nn) {
            H4 h;
            for (int oo = 0; oo < 4; ++oo) h.e[oo] = (_Float16)(acc[oo][nn] + bias[oo]);
            *(short4*)&dst[(size_t)(n0 + nn) * CQn + o0] = h.v;
        }
    } else {
        // Vg[b][ntile][c][pos]
        _Float16* dst = Vg + (size_t)(b * 64 + ntile) * 128 * 64;
        const int og = obase + o0;
        const int a  = n0 >> 2;
        const int h  = a >> 3, qd = a & 7;
        const int pbase = h * 32 + (qd & 3) * 8 + (qd >> 2) * 4;
        for (int oo = 0; oo < 4; ++oo) {
            H4 hh;
            for (int nn = 0; nn < 4; ++nn) hh.e[nn] = (_Float16)(acc[oo][nn] + bias[oo]);
            *(short4*)&dst[(size_t)(og + oo) * 64 + pbase] = hh.v;
        }
    }
}

// ---------------------------------------------------------------------------
// Kernel 2: MFMA flash attention, KV split across blocks (grid z = s).
// 256 thr, launch_bounds(256,4) -> 128-VGPR cap, 32 KB LDS (V dbuf only)
// -> exactly 4 blocks/CU resident for the 1024-block grid (no tail).
// K: direct global b128 gathers into registers (single-buffered, L1/L2 path).
// V: fragment-major tiles staged async via global_load_lds (16B granules,
// source XOR (granule^(row&7)) -> read b128 at (c row, (4h+g)^(c&7) granule)
// is conflict-free per quarter-wave. PV B-fragment = one b128 = h8_t direct.
// Swapped QK^T (D=S^T, col=query=ln); kappa(e,g)=4g+(e&3)+16(e>>2) pairing.
// Defer-max (THR=8). One barrier per tile (drains next tile's V stage).
// ---------------------------------------------------------------------------
__device__ __forceinline__ void gload16(const void* g, void* l) {
    __builtin_amdgcn_global_load_lds(
        (const __attribute__((address_space(1))) u32*)g,
        (__attribute__((address_space(3))) u32*)l, 16, 0, 0);
}

__global__ __launch_bounds__(256, 4) void attn_split(
    const _Float16* __restrict__ Qh, const _Float16* __restrict__ Kh,
    const _Float16* __restrict__ Vg, float* __restrict__ out,
    float* __restrict__ pPart, float* __restrict__ pMl, int S)
{
    __shared__ __align__(16) char smem[32768];   // V double buffer (2 x 16 KB)

    const int tid  = threadIdx.x;
    const int w    = tid >> 6;
    const int lane = tid & 63;
    const int g    = lane >> 4;
    const int ln   = lane & 15;
    const int it   = blockIdx.x;
    const int b    = blockIdx.y;
    const int s    = blockIdx.z;
    const int wib  = it * 64 + w * 16;
    const int njt  = 64 / S;

    // Persistent Q fragments (B operand: col=ln -> query wib+ln)
    const _Float16* qrow = Qh + ((size_t)(b * Nn + wib + ln)) * CQn + 8 * g;
    const h8_t q0 = *(const h8_t*)(qrow);
    const h8_t q1 = *(const h8_t*)(qrow + 32);

    const _Float16* Kb  = Kh + (size_t)b * Nn * CQn;
    const _Float16* Vgb = Vg + (size_t)b * 64 * 8192;   // 64 tiles x 8192 f16

    // V staging source offsets (f16) within a tile: LDS granule G holds
    // Vg-tile[row = G>>3][((G&7) ^ (row&7)) * 8 .. +7]
    int vsrc[4];
    #pragma unroll
    for (int u = 0; u < 4; ++u) {
        int G   = u * 256 + tid;
        int row = G >> 3;
        vsrc[u] = row * 64 + (((G & 7) ^ (row & 7)) * 8);
    }

    // V read offsets (bytes): row = cs*16+ln (row&7 = ln&7), granule (4h+g)^r7
    const int r7  = ln & 7;
    const int vb0 = ln * 128 + (((    g) ^ r7) << 4);   // h=0 -> pa0's B mate
    const int vb1 = ln * 128 + (((4 + g) ^ r7) << 4);   // h=1 -> pa1's B mate

    auto stage = [&](int voff, int jt) {
        const _Float16* src = Vgb + (size_t)jt * 8192;
        #pragma unroll
        for (int u = 0; u < 4; ++u)
            gload16(src + vsrc[u], smem + voff + u * 4096 + w * 1024);
    };

    f32x4 oacc[8];
    #pragma unroll
    for (int i = 0; i < 8; ++i) oacc[i] = (f32x4){0.f, 0.f, 0.f, 0.f};
    float m_run = -3.0e38f, l_run = 0.f;

    const int jt0 = s * njt;
    stage(0, jt0);
    __syncthreads();

    for (int t = 0; t < njt; ++t) {
        // 1) K fragments for tile t (direct global gathers, issued first)
        h8_t kf0[4], kf1[4];
        const _Float16* kbase = Kb + (size_t)((jt0 + t) * 64 + ln) * CQn + 8 * g;
        #pragma unroll
        for (int js = 0; js < 4; ++js) {
            kf0[js] = *(const h8_t*)(kbase + js * 16 * CQn);
            kf1[js] = *(const h8_t*)(kbase + js * 16 * CQn + 32);
        }

        // 2) stage next V tile into the other buffer (drained at barrier)
        if (t + 1 < njt) stage(((t + 1) & 1) ? 16384 : 0, jt0 + t + 1);

        // 3) scores: st[js] rows = keys js*16+4g+r, col = query ln
        f32x4 st[4];
        __builtin_amdgcn_s_setprio(1);
        #pragma unroll
        for (int js = 0; js < 4; ++js) {
            st[js] = (f32x4){0.f, 0.f, 0.f, 0.f};
            st[js] = __builtin_amdgcn_mfma_f32_16x16x32_f16(kf0[js], q0, st[js], 0, 0, 0);
            st[js] = __builtin_amdgcn_mfma_f32_16x16x32_f16(kf1[js], q1, st[js], 0, 0, 0);
        }
        __builtin_amdgcn_s_setprio(0);

        // 4) online softmax with defer-max (THR=8)
        float tmax = st[0][0];
        #pragma unroll
        for (int js = 0; js < 4; ++js)
            #pragma unroll
            for (int r = 0; r < 4; ++r) tmax = fmaxf(tmax, st[js][r]);
        tmax = fmaxf(tmax, __shfl_xor(tmax, 16));
        tmax = fmaxf(tmax, __shfl_xor(tmax, 32));
        if (__any(tmax > m_run + 8.f)) {
            const float mnew  = fmaxf(m_run, tmax);
            const float alpha = __expf(m_run - mnew);
            const float a0 = __shfl(alpha, 4 * g + 0);
            const float a1 = __shfl(alpha, 4 * g + 1);
            const float a2 = __shfl(alpha, 4 * g + 2);
            const float a3 = __shfl(alpha, 4 * g + 3);
            #pragma unroll
            for (int cs = 0; cs < 8; ++cs) {
                oacc[cs][0] *= a0; oacc[cs][1] *= a1;
                oacc[cs][2] *= a2; oacc[cs][3] *= a3;
            }
            l_run *= alpha;
            m_run = mnew;
        }
        float ts = 0.f;
        #pragma unroll
        for (int js = 0; js < 4; ++js)
            #pragma unroll
            for (int r = 0; r < 4; ++r) {
                float p = __expf(st[js][r] - m_run);
                st[js][r] = p;
                ts += p;
            }
        ts += __shfl_xor(ts, 16);
        ts += __shfl_xor(ts, 32);
        l_run += ts;

        // 5) P fragments by kappa(e,g) = 4g+(e&3)+16*(e>>2)
        union H8 { h8_t h; _Float16 e[8]; };
        H8 p0u, p1u;
        #pragma unroll
        for (int r = 0; r < 4; ++r) {
            p0u.e[r]     = (_Float16)st[0][r];
            p0u.e[4 + r] = (_Float16)st[1][r];
            p1u.e[r]     = (_Float16)st[2][r];
            p1u.e[4 + r] = (_Float16)st[3][r];
        }
        const h8_t pa0 = p0u.h;
        const h8_t pa1 = p1u.h;

        // 6) PV: fragment-major V -> one b128 per (cs, half)
        const char* VU = smem + ((t & 1) ? 16384 : 0);
        __builtin_amdgcn_s_setprio(1);
        #pragma unroll
        for (int cs = 0; cs < 8; ++cs) {
            h8_t v01 = *(const h8_t*)(VU + vb0 + cs * 2048);
            h8_t v23 = *(const h8_t*)(VU + vb1 + cs * 2048);
            oacc[cs] = __builtin_amdgcn_mfma_f32_16x16x32_f16(pa0, v01, oacc[cs], 0, 0, 0);
            oacc[cs] = __builtin_amdgcn_mfma_f32_16x16x32_f16(pa1, v23, oacc[cs], 0, 0, 0);
        }
        __builtin_amdgcn_s_setprio(0);

        __syncthreads();   // drains this wave's staged V(t+1); frees buf t
    }

    if (S == 1) {
        const float lr = 1.f / l_run;
        const float l0 = __shfl(lr, 4 * g + 0);
        const float l1 = __shfl(lr, 4 * g + 1);
        const float l2 = __shfl(lr, 4 * g + 2);
        const float l3 = __shfl(lr, 4 * g + 3);
        float* ob = out + (size_t)b * Cn * Nn;
        #pragma unroll
        for (int cs = 0; cs < 8; ++cs) {
            float4 o;
            o.x = oacc[cs][0] * l0;
            o.y = oacc[cs][1] * l1;
            o.z = oacc[cs][2] * l2;
            o.w = oacc[cs][3] * l3;
            *(float4*)&ob[(size_t)(cs * 16 + ln) * Nn + wib + 4 * g] = o;
        }
    } else {
        float* pp = pPart + (((size_t)b * 64 + it) * S + s) * 8192;
        const int qloc = w * 16 + 4 * g;
        #pragma unroll
        for (int cs = 0; cs < 8; ++cs)
            *(float4*)&pp[(size_t)(cs * 16 + ln) * 64 + qloc] =
                make_float4(oacc[cs][0], oacc[cs][1], oacc[cs][2], oacc[cs][3]);
        if (g == 0) {
            float* ml = pMl + ((((size_t)b * 64 + it) * S + s) * 64 + w * 16 + ln) * 2;
            ml[0] = m_run;
            ml[1] = l_run;
        }
    }
}

// ---------------------------------------------------------------------------
// Kernel 3: flash-combine across S splits. Grid (64 it, B), 256 threads.
// ---------------------------------------------------------------------------
__global__ __launch_bounds__(256) void attn_combine(
    const float* __restrict__ pPart, const float* __restrict__ pMl,
    float* __restrict__ out, int S)
{
    const int it  = blockIdx.x;
    const int b   = blockIdx.y;
    const int tid = threadIdx.x;

    __shared__ float wgt[4][64];
    __shared__ float linv[64];

    if (tid < 64) {
        const float* mlb = pMl + (((size_t)b * 64 + it) * S * 64 + tid) * 2;
        float ms[4], ls[4], m = -3.0e38f;
        for (int s = 0; s < S; ++s) {
            ms[s] = mlb[s * 128 + 0];
            ls[s] = mlb[s * 128 + 1];
            m = fmaxf(m, ms[s]);
        }
        float l = 0.f;
        for (int s = 0; s < S; ++s) {
            float wv = __expf(ms[s] - m);
            wgt[s][tid] = wv;
            l += wv * ls[s];
        }
        linv[tid] = 1.f / l;
    }
    __syncthreads();

    const int c  = tid >> 1;
    const int q0 = (tid & 1) * 32;
    const float* base = pPart + ((size_t)b * 64 + it) * S * 8192 + (size_t)c * 64 + q0;

    float acc[32];
    #pragma unroll
    for (int k = 0; k < 32; ++k) acc[k] = 0.f;
    for (int s = 0; s < S; ++s) {
        const float* ps = base + (size_t)s * 8192;
        #pragma unroll
        for (int k = 0; k < 32; k += 4) {
            float4 v = *(const float4*)(ps + k);
            acc[k + 0] += wgt[s][q0 + k + 0] * v.x;
            acc[k + 1] += wgt[s][q0 + k + 1] * v.y;
            acc[k + 2] += wgt[s][q0 + k + 2] * v.z;
            acc[k + 3] += wgt[s][q0 + k + 3] * v.w;
        }
    }
    float* ob = out + ((size_t)b * Cn + c) * Nn + it * 64 + q0;
    #pragma unroll
    for (int k = 0; k < 32; k += 4) {
        float4 o;
        o.x = acc[k + 0] * linv[q0 + k + 0];
        o.y = acc[k + 1] * linv[q0 + k + 1];
        o.z = acc[k + 2] * linv[q0 + k + 2];
        o.w = acc[k + 3] * linv[q0 + k + 3];
        *(float4*)&ob[k] = o;
    }
}

extern "C" void kernel_launch(void* const* d_in, const int* in_sizes, int n_in,
                              void* d_out, int out_size, void* d_ws, size_t ws_size,
                              hipStream_t stream) {
    const float* x  = (const float*)d_in[0];
    const float* Wq = (const float*)d_in[1];
    const float* bq = (const float*)d_in[2];
    const float* Wk = (const float*)d_in[3];
    const float* bk = (const float*)d_in[4];
    const float* Wv = (const float*)d_in[5];
    const float* bv = (const float*)d_in[6];
    float* out = (float*)d_out;

    _Float16* ws = (_Float16*)d_ws;
    _Float16* Qh = ws;
    _Float16* Kh = ws + 1048576;
    _Float16* Vg = ws + 2097152;

    int S = 1;
    if (ws_size >= QKV_BYTES + 4 * (PART_PER_S + ML_PER_S)) S = 4;
    else if (ws_size >= QKV_BYTES + 2 * (PART_PER_S + ML_PER_S)) S = 2;

    float* pPart = (float*)((char*)d_ws + QKV_BYTES);
    float* pMl   = (float*)((char*)d_ws + QKV_BYTES + (size_t)S * PART_PER_S);

    dim3 gproj(Nn / 64, 4, Bn);
    qkv_proj<<<gproj, 256, 0, stream>>>(x, Wq, bq, Wk, bk, Wv, bv, Qh, Kh, Vg);

    dim3 gattn(Nn / 64, Bn, S);
    attn_split<<<gattn, 256, 0, stream>>>(Qh, Kh, Vg, out, pPart, pMl, S);

    if (S > 1) {
        dim3 gcomb(Nn / 64, Bn);
        attn_combine<<<gcomb, 256, 0, stream>>>(pPart, pMl, out, S);
    }
}